// Round 3
// baseline (73.316 us; speedup 1.0000x reference)
//
#include <hip/hip_runtime.h>
#include <hip/hip_bf16.h>

#define NB 4096

typedef short v8s __attribute__((ext_vector_type(8)));
typedef float v4f __attribute__((ext_vector_type(4)));

__device__ __forceinline__ float bf2f(unsigned short u) {
    return __uint_as_float(((unsigned int)u) << 16);
}

// ws layout: part[4096*32] float2 (n,d per row per col-block) = 1 MB

// One block = 128x128 Gram tile via bf16 MFMA, fully fused:
// fp32->bf16 staging, per-row sq, dist->exp->masked num/den, partial write.
__global__ __launch_bounds__(256) void snn_mfma(const float* __restrict__ x,
        const int* __restrict__ y, float2* __restrict__ part,
        float* __restrict__ out) {
    // tiles padded to stride 136 bf16 (68 dw) -> uniform bank spread for
    // ds_read_b128 fragments; part[] reuses the same LDS post-MFMA.
    __shared__ __align__(16) union {
        unsigned short tiles[2 * 128 * 136];   // 69632 B
        float part[2 * 128 * 34];              // [wn][row][17 float2]
    } sm;
    __shared__ float sqi[128], sqj[128];
    __shared__ int yi[128], yj[128];

    const int tid = threadIdx.x;
    const int wave = tid >> 6;
    const int lane = tid & 63;
    const int wm = wave >> 1;      // row half
    const int wn = wave & 1;       // col half
    const int lr = lane & 15;
    const int q  = lane >> 4;
    const int i0 = blockIdx.x * 128;
    const int j0 = blockIdx.y * 128;

    if (blockIdx.x == 0 && blockIdx.y == 0 && tid == 0) out[0] = 0.f;

    unsigned short* At = sm.tiles;
    unsigned short* Bt = sm.tiles + 128 * 136;
    const float4* xg = (const float4*)x;   // 32 float4 per row

    // stage A+B tiles: thread handles 8 chunks of 8 floats per tile
    #pragma unroll
    for (int it = 0; it < 8; ++it) {
        int p = it * 256 + tid;            // 8-float chunk index 0..2047
        int row = p >> 4, c2 = p & 15;
        float4 a0 = xg[(i0 + row) * 32 + c2 * 2];
        float4 a1 = xg[(i0 + row) * 32 + c2 * 2 + 1];
        float4 b0 = xg[(j0 + row) * 32 + c2 * 2];
        float4 b1 = xg[(j0 + row) * 32 + c2 * 2 + 1];
        v8s av, bv;
        const float af_[8] = {a0.x, a0.y, a0.z, a0.w, a1.x, a1.y, a1.z, a1.w};
        const float bf_[8] = {b0.x, b0.y, b0.z, b0.w, b1.x, b1.y, b1.z, b1.w};
        #pragma unroll
        for (int e = 0; e < 8; ++e) {
            __hip_bfloat16 ha = __float2bfloat16(af_[e]);
            __hip_bfloat16 hb = __float2bfloat16(bf_[e]);
            av[e] = *(short*)&ha;
            bv[e] = *(short*)&hb;
        }
        *(v8s*)&At[row * 136 + c2 * 8] = av;
        *(v8s*)&Bt[row * 136 + c2 * 8] = bv;
    }
    if (tid < 128) yi[tid] = y[i0 + tid];
    else           yj[tid - 128] = y[j0 + tid - 128];
    __syncthreads();

    // per-row squared norm from the bf16 tiles (consistent with MFMA dot:
    // diagonal dist comes out exactly 0)
    {
        int r = tid & 127;
        const v8s* rp = (const v8s*)((tid < 128) ? &At[r * 136] : &Bt[r * 136]);
        float s = 0.f;
        #pragma unroll
        for (int c = 0; c < 16; ++c) {
            v8s v = rp[c];
            #pragma unroll
            for (int e = 0; e < 8; ++e) {
                float f = bf2f((unsigned short)v[e]);
                s += f * f;
            }
        }
        if (tid < 128) sqi[r] = s; else sqj[r] = s;
    }

    v4f acc[4][4];
    #pragma unroll
    for (int mt = 0; mt < 4; ++mt)
        #pragma unroll
        for (int nt = 0; nt < 4; ++nt)
            #pragma unroll
            for (int r = 0; r < 4; ++r) acc[mt][nt][r] = 0.f;

    #pragma unroll
    for (int kk = 0; kk < 4; ++kk) {
        v8s af[4], bf[4];
        #pragma unroll
        for (int mt = 0; mt < 4; ++mt)
            af[mt] = *(const v8s*)&At[(wm * 64 + mt * 16 + lr) * 136 + kk * 32 + q * 8];
        #pragma unroll
        for (int nt = 0; nt < 4; ++nt)
            bf[nt] = *(const v8s*)&Bt[(wn * 64 + nt * 16 + lr) * 136 + kk * 32 + q * 8];
        #pragma unroll
        for (int mt = 0; mt < 4; ++mt)
            #pragma unroll
            for (int nt = 0; nt < 4; ++nt)
                acc[mt][nt] = __builtin_amdgcn_mfma_f32_16x16x32_bf16(
                    af[mt], bf[nt], acc[mt][nt], 0, 0, 0);
    }

    __syncthreads();   // tile reads (MFMA + sq) done before part[] overwrites

    float sqj_r[4]; int yj_r[4], jg[4];
    #pragma unroll
    for (int nt = 0; nt < 4; ++nt) {
        int jc = wn * 64 + nt * 16 + lr;
        sqj_r[nt] = sqj[jc]; yj_r[nt] = yj[jc]; jg[nt] = j0 + jc;
    }
    #pragma unroll
    for (int mt = 0; mt < 4; ++mt) {
        #pragma unroll
        for (int r = 0; r < 4; ++r) {
            int rloc = wm * 64 + mt * 16 + q * 4 + r;   // C/D: row = q*4+reg
            float si = sqi[rloc]; int yir = yi[rloc]; int ig = i0 + rloc;
            float n = 0.f, d = 0.f;
            #pragma unroll
            for (int nt = 0; nt < 4; ++nt) {
                float dist = fmaxf(si + sqj_r[nt] - 2.f * acc[mt][nt][r], 0.f);
                float e = __builtin_amdgcn_exp2f(dist * -0.014426950408889634f);
                d += e;
                bool ok = (yir == yj_r[nt]) && (ig != jg[nt]);
                n += ok ? e : 0.f;
            }
            *(float2*)&sm.part[((wn * 128 + rloc) * 17 + lr) * 2] = make_float2(n, d);
        }
    }
    __syncthreads();

    // block reduction: 2 threads per row, then one float2 store per row
    {
        int row = tid >> 1, h = tid & 1;
        const float2* p = (const float2*)&sm.part[(h * 128 + row) * 34];
        float sn = 0.f, sd = 0.f;
        #pragma unroll
        for (int c = 0; c < 16; ++c) { float2 v = p[c]; sn += v.x; sd += v.y; }
        sn += __shfl_down(sn, 1); sd += __shfl_down(sd, 1);
        if (h == 0) part[(i0 + row) * 32 + blockIdx.y] = make_float2(sn, sd);
    }
}

__global__ __launch_bounds__(256) void snn_final(const float2* __restrict__ part,
        float* __restrict__ out) {
    __shared__ float wsum[4];
    int row = blockIdx.x * 256 + threadIdx.x;
    const float4* p = (const float4*)&part[row * 32];   // 16 float4 = 32 float2
    float n = 0.f, d = 0.f;
    #pragma unroll
    for (int c = 0; c < 16; ++c) {
        float4 v = p[c];
        n += v.x + v.z; d += v.y + v.w;
    }
    float l = __logf(d) - __logf(n);
    #pragma unroll
    for (int off = 32; off > 0; off >>= 1) l += __shfl_down(l, off);
    int wid = threadIdx.x >> 6;
    if ((threadIdx.x & 63) == 0) wsum[wid] = l;
    __syncthreads();
    if (threadIdx.x == 0) {
        float s = wsum[0] + wsum[1] + wsum[2] + wsum[3];
        atomicAdd(out, s * (1.0f / NB));
    }
}

extern "C" void kernel_launch(void* const* d_in, const int* in_sizes, int n_in,
                              void* d_out, int out_size, void* d_ws, size_t ws_size,
                              hipStream_t stream) {
    const float* x = (const float*)d_in[0];
    const int*   y = (const int*)d_in[1];
    float* out = (float*)d_out;
    float2* part = (float2*)d_ws;

    dim3 grid(NB / 128, NB / 128);
    snn_mfma<<<grid, 256, 0, stream>>>(x, y, part, out);
    snn_final<<<NB / 256, 256, 0, stream>>>(part, out);
}

// Round 4
// 72.339 us; speedup vs baseline: 1.0135x; 1.0135x over previous
//
#include <hip/hip_runtime.h>
#include <hip/hip_bf16.h>

#define NB 4096

typedef short v8s __attribute__((ext_vector_type(8)));
typedef float v4f __attribute__((ext_vector_type(4)));

// ws layout: part[4096*32] float2 (1 MB) | sq[4096] f32 (16 KB) | xb[4096*128] bf16 (1 MB)

__global__ __launch_bounds__(256) void prep_kernel(const float* __restrict__ x,
        float* __restrict__ sq, unsigned short* __restrict__ xb,
        float* __restrict__ out) {
    int tid = threadIdx.x;
    int row = blockIdx.x * 8 + (tid >> 5);
    int lane = tid & 31;
    const float4* xg = (const float4*)x;
    float4 v = xg[row * 32 + lane];
    __hip_bfloat16 h0 = __float2bfloat16(v.x), h1 = __float2bfloat16(v.y);
    __hip_bfloat16 h2 = __float2bfloat16(v.z), h3 = __float2bfloat16(v.w);
    ushort4 u4;
    u4.x = *(unsigned short*)&h0; u4.y = *(unsigned short*)&h1;
    u4.z = *(unsigned short*)&h2; u4.w = *(unsigned short*)&h3;
    ((ushort4*)xb)[row * 32 + lane] = u4;
    // sq from the bf16-rounded values (consistent with the MFMA dot -> diag dist == 0)
    float f0 = __bfloat162float(h0), f1 = __bfloat162float(h1);
    float f2 = __bfloat162float(h2), f3 = __bfloat162float(h3);
    float s = f0 * f0 + f1 * f1 + f2 * f2 + f3 * f3;
    #pragma unroll
    for (int off = 16; off > 0; off >>= 1) s += __shfl_down(s, off);
    if (lane == 0) sq[row] = s;
    if (blockIdx.x == 0 && tid == 0) out[0] = 0.f;
}

// Triangular grid: block t -> (bx <= by). Computes 128x128 tile S = Xbx . Xby^T,
// emits row-partials (rows of tile bx, slot by) and, for bx!=by, col-partials
// (rows of tile by, slot bx) exploiting symmetry.
__global__ __launch_bounds__(256) void snn_mfma(const unsigned short* __restrict__ xb,
        const int* __restrict__ y, const float* __restrict__ sqg,
        float2* __restrict__ part) {
    __shared__ __align__(16) union {
        unsigned short tiles[2 * 128 * 136];   // 69632 B, stride 136 bf16: conflict-free b128 frags
        float part[2 * 128 * 34];              // row partials [wn][row][17 float2] = 8704 floats
    } sm;
    __shared__ float sqi[128], sqj[128];
    __shared__ int yi[128], yj[128];
    float2* partC = (float2*)&sm.part[2 * 128 * 34];   // col partials [wm][128], 1024 floats

    const int tid = threadIdx.x;
    const int wave = tid >> 6;
    const int lane = tid & 63;
    const int wm = wave >> 1;
    const int wn = wave & 1;
    const int lr = lane & 15;
    const int q  = lane >> 4;

    // triangular decode: t = by*(by+1)/2 + bx, bx <= by
    int t = blockIdx.x;
    int by = (int)((sqrtf(8.0f * (float)t + 1.0f) - 1.0f) * 0.5f);
    if (by * (by + 1) / 2 > t) --by;
    if ((by + 1) * (by + 2) / 2 <= t) ++by;
    int bx = t - by * (by + 1) / 2;
    const int i0 = bx * 128;
    const int j0 = by * 128;
    const bool offdiag = (bx != by);

    unsigned short* At = sm.tiles;
    unsigned short* Bt = sm.tiles + 128 * 136;
    const v8s* xg = (const v8s*)xb;   // 16 chunks of 8 bf16 per row

    #pragma unroll
    for (int r = 0; r < 8; ++r) {
        int c = r * 256 + tid;
        int row = c >> 4, cc = c & 15;
        *(v8s*)&At[row * 136 + cc * 8] = xg[(i0 + row) * 16 + cc];
        *(v8s*)&Bt[row * 136 + cc * 8] = xg[(j0 + row) * 16 + cc];
    }
    if (tid < 128) { sqi[tid] = sqg[i0 + tid]; yi[tid] = y[i0 + tid]; }
    else { sqj[tid - 128] = sqg[j0 + tid - 128]; yj[tid - 128] = y[j0 + tid - 128]; }
    __syncthreads();

    v4f acc[4][4];
    #pragma unroll
    for (int mt = 0; mt < 4; ++mt)
        #pragma unroll
        for (int nt = 0; nt < 4; ++nt)
            #pragma unroll
            for (int r = 0; r < 4; ++r) acc[mt][nt][r] = 0.f;

    #pragma unroll
    for (int kk = 0; kk < 4; ++kk) {
        v8s af[4], bf[4];
        #pragma unroll
        for (int mt = 0; mt < 4; ++mt)
            af[mt] = *(const v8s*)&At[(wm * 64 + mt * 16 + lr) * 136 + kk * 32 + q * 8];
        #pragma unroll
        for (int nt = 0; nt < 4; ++nt)
            bf[nt] = *(const v8s*)&Bt[(wn * 64 + nt * 16 + lr) * 136 + kk * 32 + q * 8];
        #pragma unroll
        for (int mt = 0; mt < 4; ++mt)
            #pragma unroll
            for (int nt = 0; nt < 4; ++nt)
                acc[mt][nt] = __builtin_amdgcn_mfma_f32_16x16x32_bf16(
                    af[mt], bf[nt], acc[mt][nt], 0, 0, 0);
    }

    __syncthreads();   // tile reads done before part[] overwrites

    float sqj_r[4]; int yj_r[4], jg[4];
    #pragma unroll
    for (int nt = 0; nt < 4; ++nt) {
        int jc = wn * 64 + nt * 16 + lr;
        sqj_r[nt] = sqj[jc]; yj_r[nt] = yj[jc]; jg[nt] = j0 + jc;
    }
    float colN[4] = {0.f, 0.f, 0.f, 0.f};
    float colD[4] = {0.f, 0.f, 0.f, 0.f};

    #pragma unroll
    for (int mt = 0; mt < 4; ++mt) {
        #pragma unroll
        for (int r = 0; r < 4; ++r) {
            int rloc = wm * 64 + mt * 16 + q * 4 + r;   // C/D: row = q*4+reg
            float si = sqi[rloc]; int yir = yi[rloc]; int ig = i0 + rloc;
            float n = 0.f, d = 0.f;
            #pragma unroll
            for (int nt = 0; nt < 4; ++nt) {
                float dist = fmaxf(si + sqj_r[nt] - 2.f * acc[mt][nt][r], 0.f);
                float e = __builtin_amdgcn_exp2f(dist * -0.014426950408889634f);
                d += e;
                bool ok = (yir == yj_r[nt]) && (ig != jg[nt]);
                float ne = ok ? e : 0.f;
                n += ne;
                colN[nt] += ne;   // symmetric contribution to row jg[nt]
                colD[nt] += e;
            }
            *(float2*)&sm.part[((wn * 128 + rloc) * 17 + lr) * 2] = make_float2(n, d);
        }
    }
    // col partials: reduce across the 4 quads (lanes sharing lr)
    if (offdiag) {
        #pragma unroll
        for (int nt = 0; nt < 4; ++nt) {
            float cn = colN[nt], cd = colD[nt];
            cn += __shfl_xor(cn, 16); cd += __shfl_xor(cd, 16);
            cn += __shfl_xor(cn, 32); cd += __shfl_xor(cd, 32);
            if (q == 0) partC[wm * 128 + wn * 64 + nt * 16 + lr] = make_float2(cn, cd);
        }
    }
    __syncthreads();

    // block reduction: rows (2 threads/row over 16 float2 x 2 wn-halves)
    {
        int row = tid >> 1, h = tid & 1;
        const float2* p = (const float2*)&sm.part[(h * 128 + row) * 34];
        float sn = 0.f, sd = 0.f;
        #pragma unroll
        for (int c = 0; c < 16; ++c) { float2 v = p[c]; sn += v.x; sd += v.y; }
        sn += __shfl_down(sn, 1); sd += __shfl_down(sd, 1);
        if (h == 0) part[(i0 + row) * 32 + by] = make_float2(sn, sd);
    }
    // cols: sum the two wm halves, one slot per col-row
    if (offdiag && tid < 128) {
        float2 a = partC[tid], b = partC[128 + tid];
        part[(j0 + tid) * 32 + bx] = make_float2(a.x + b.x, a.y + b.y);
    }
}

__global__ __launch_bounds__(256) void snn_final(const float2* __restrict__ part,
        float* __restrict__ out) {
    __shared__ float wsum[4];
    int row = blockIdx.x * 256 + threadIdx.x;
    const float4* p = (const float4*)&part[row * 32];
    float n = 0.f, d = 0.f;
    #pragma unroll
    for (int c = 0; c < 16; ++c) {
        float4 v = p[c];
        n += v.x + v.z; d += v.y + v.w;
    }
    float l = __logf(d) - __logf(n);
    #pragma unroll
    for (int off = 32; off > 0; off >>= 1) l += __shfl_down(l, off);
    int wid = threadIdx.x >> 6;
    if ((threadIdx.x & 63) == 0) wsum[wid] = l;
    __syncthreads();
    if (threadIdx.x == 0) {
        float s = wsum[0] + wsum[1] + wsum[2] + wsum[3];
        atomicAdd(out, s * (1.0f / NB));
    }
}

extern "C" void kernel_launch(void* const* d_in, const int* in_sizes, int n_in,
                              void* d_out, int out_size, void* d_ws, size_t ws_size,
                              hipStream_t stream) {
    const float* x = (const float*)d_in[0];
    const int*   y = (const int*)d_in[1];
    float* out = (float*)d_out;
    float2* part = (float2*)d_ws;
    float* sq = (float*)((char*)d_ws + (1 << 20));
    unsigned short* xb = (unsigned short*)((char*)d_ws + (1 << 20) + (16 << 10));

    prep_kernel<<<NB / 8, 256, 0, stream>>>(x, sq, xb, out);
    snn_mfma<<<528, 256, 0, stream>>>(xb, y, sq, part);
    snn_final<<<NB / 256, 256, 0, stream>>>(part, out);
}